// Round 5
// baseline (473.295 us; speedup 1.0000x reference)
//
#include <hip/hip_runtime.h>
#include <math.h>

#define GAS __attribute__((address_space(1)))
#define LAS __attribute__((address_space(3)))

typedef __attribute__((ext_vector_type(4))) float f32x4;
typedef __attribute__((ext_vector_type(8))) short bf16x8;
typedef __attribute__((ext_vector_type(4))) short bf16x4;

#define MFMA(a,b,c)   __builtin_amdgcn_mfma_f32_16x16x32_bf16((a),(b),(c),0,0,0)
#define MFMA16(a,b,c) __builtin_amdgcn_mfma_f32_16x16x16bf16_1k((a),(b),(c),0,0,0)

__device__ __forceinline__ void gl_lds16(const void* g, void* l) {
    __builtin_amdgcn_global_load_lds((const GAS unsigned*)g, (LAS unsigned*)l, 16, 0, 0);
}

__device__ __forceinline__ short f2bf(float f) {
    union { float f; unsigned u; } v; v.f = f;
    unsigned r = (v.u + 0x7fff + ((v.u >> 16) & 1)) >> 16;   // RNE
    return (short)r;
}

__device__ __forceinline__ void castN(const float* __restrict__ s, short* __restrict__ d,
                                      int n4, int gid, int gsz) {
    for (int i = gid; i < n4; i += gsz) {
        float4 v = ((const float4*)s)[i];
        short4 o = make_short4(f2bf(v.x), f2bf(v.y), f2bf(v.z), f2bf(v.w));
        ((short4*)d)[i] = o;
    }
}

__global__ __launch_bounds__(256)
void cast_all(const float* __restrict__ x,  const float* __restrict__ wq,
              const float* __restrict__ wk, const float* __restrict__ wv,
              const float* __restrict__ wo,
              short* __restrict__ xb, short* __restrict__ wqkv, short* __restrict__ wob) {
    int gid = blockIdx.x*256 + threadIdx.x;
    int gsz = gridDim.x*256;
    castN(x,  xb,               (4096*2048)/4, gid, gsz);
    castN(wq, wqkv,             (2048*2048)/4, gid, gsz);
    castN(wk, wqkv + 2048*2048, (512*2048)/4,  gid, gsz);
    castN(wv, wqkv + 2560*2048, (512*2048)/4,  gid, gsz);
    castN(wo, wob,              (2048*2048)/4, gid, gsz);
}

// m97-style bf16 MFMA GEMM: C(M,N) = A(M,K) @ Bw(N,K)^T, 128x128 tile, BK=32.
// MODE 0: fp32 row-major to Cf (Wo path).
// MODE 1: fused QKV epilogue: RoPE via shfl_xor(1) + bf16 stores.
//         Q pre-scaled by 0.125*log2e (attn softmax runs in exp2 domain, shift=0).
//         V stored TRANSPOSED (B,8,64d,1024t) so attention A-frags are contiguous.
template<int MODE>
__global__ __launch_bounds__(256)
void gemm_mfma(const short* __restrict__ A, const short* __restrict__ Bw,
               int M, int N, int K, float* __restrict__ Cf,
               short* __restrict__ qo, short* __restrict__ ko, short* __restrict__ vo,
               const float* __restrict__ cosb, const float* __restrict__ sinb)
{
    __shared__ short As[128*32];
    __shared__ short Bs[128*32];
    const int tid = threadIdx.x;
    const int lane = tid & 63, wv = tid >> 6;
    const int wm = wv >> 1, wn = wv & 1;
    const int m0 = blockIdx.y*128, n0 = blockIdx.x*128;
    const int l15 = lane & 15, quad = lane >> 4;

    f32x4 acc[4][4] = {};

    const int srow = lane >> 2, skc = (lane & 3)*8;
    const short* gA0 = A  + (size_t)(m0 + wv*32 + srow)*K + skc;
    const short* gB0 = Bw + (size_t)(n0 + wv*32 + srow)*K + skc;
    short* lA = As + wv*1024;
    short* lB = Bs + wv*1024;

    for (int k0 = 0; k0 < K; k0 += 32) {
        __syncthreads();
        gl_lds16(gA0 + k0,        lA);
        gl_lds16(gA0 + 16*K + k0, lA + 512);
        gl_lds16(gB0 + k0,        lB);
        gl_lds16(gB0 + 16*K + k0, lB + 512);
        __syncthreads();
        bf16x8 af[4], bfr[4];
        #pragma unroll
        for (int t = 0; t < 4; t++) {
            af[t]  = *(const bf16x8*)&As[(wm*64 + t*16 + l15)*32 + quad*8];
            bfr[t] = *(const bf16x8*)&Bs[(wn*64 + t*16 + l15)*32 + quad*8];
        }
        #pragma unroll
        for (int i = 0; i < 4; i++)
            #pragma unroll
            for (int j = 0; j < 4; j++)
                acc[i][j] = MFMA(af[i], bfr[j], acc[i][j]);
    }

    if (MODE == 0) {
        #pragma unroll
        for (int i = 0; i < 4; i++)
            #pragma unroll
            for (int j = 0; j < 4; j++) {
                int n  = n0 + wn*64 + j*16 + l15;
                int mb = m0 + wm*64 + i*16 + quad*4;
                #pragma unroll
                for (int r = 0; r < 4; r++)
                    Cf[(size_t)(mb + r)*N + n] = acc[i][j][r];
            }
    } else {
        #pragma unroll
        for (int i = 0; i < 4; i++)
            #pragma unroll
            for (int j = 0; j < 4; j++) {
                int n  = n0 + wn*64 + j*16 + l15;   // 16-range never crosses a 64-boundary
                int mb = m0 + wm*64 + i*16 + quad*4;
                if (n >= 2560) {                     // V: transposed store, 4 consecutive t
                    int bq = mb >> 10, t0 = mb & 1023;
                    int hv = (n - 2560) >> 6, d = (n - 2560) & 63;
                    short4 s4 = make_short4(f2bf(acc[i][j][0]), f2bf(acc[i][j][1]),
                                            f2bf(acc[i][j][2]), f2bf(acc[i][j][3]));
                    *(short4*)&vo[(((size_t)(bq*8 + hv)*64 + d) << 10) + t0] = s4;
                } else {
                    #pragma unroll
                    for (int r = 0; r < 4; r++) {
                        int m = mb + r;
                        int b = m >> 10, t = m & 1023;
                        float val = acc[i][j][r];
                        float part = __shfl_xor(val, 1);
                        int d2 = (n & 63) >> 1;
                        float c = cosb[t*32 + d2], s = sinb[t*32 + d2];
                        val = (n & 1) ? (part*s + val*c) : (val*c - part*s);
                        if (n < 2048) {
                            val *= 0.18033688f;      // 64^-0.5 * log2(e)
                            qo[(((size_t)(b*32 + (n>>6))*1024 + t) << 6) + (n & 63)] = f2bf(val);
                        } else {
                            ko[(((size_t)(b*8 + ((n-2048)>>6))*1024 + t) << 6) + ((n-2048) & 63)] = f2bf(val);
                        }
                    }
                }
            }
    }
}

__device__ __forceinline__ void stage_k(const short* __restrict__ base, short* dst,
                                        int wv, int lane) {
    #pragma unroll
    for (int jj = 0; jj < 2; jj++) {
        int j = wv*2 + jj;
        int kc = j >> 2, kr = (j & 3)*16 + (lane >> 2), dc = (lane & 3)*8;
        gl_lds16(base + (size_t)kr*64 + kc*32 + dc, dst + j*512);
    }
}

// MFMA flash attention, transposed-S formulation. S^T = K Q^T via 16x16x32
// (A=K frag from LDS, B=Q frag from regs); the S^T C-layout (col=q=l15,
// row=key=quad*4+r) IS the B-operand layout of 16x16x16, so P^T feeds
// O^T = V^T P^T with zero cross-lane traffic. V^T A-frags are 8-byte
// contiguous global loads (vt_ws is (B,8,64d,1024t)). Q loaded once from
// global. Shift-free exp2 softmax, scalar lsum, reduced once at the end.
// LDS = K double-buffer only (16 KB); ONE barrier per 64-key chunk.
__global__ __launch_bounds__(256)
void attn_mfma(const short* __restrict__ q_ws, const short* __restrict__ k_ws,
               const short* __restrict__ vt_ws, short* __restrict__ o_ws)
{
    __shared__ short Ks[2][4096];     // [kc2][64k][32d], double-buffered

    const int tid = threadIdx.x, lane = tid & 63, wv = tid >> 6;
    const int qt = 15 - blockIdx.x;              // big tiles dispatch first
    const int h = blockIdx.y, b = blockIdx.z;
    const size_t qbase  = ((size_t)(b*32 + h))     << 16;
    const size_t kvbase = ((size_t)(b*8 + (h>>2))) << 16;
    const int l15 = lane & 15, quad = lane >> 4;
    const int nc = qt + 1;

    stage_k(k_ws + kvbase, Ks[0], wv, lane);     // K chunk 0

    // Q B-fragments direct from global: row q = wv*16+l15, k=d = quad*8+[0..7] (+32)
    const short* qp = q_ws + qbase + (size_t)(qt*64 + wv*16 + l15)*64 + quad*8;
    bf16x8 aq0 = *(const bf16x8*)qp;
    bf16x8 aq1 = *(const bf16x8*)(qp + 32);

    f32x4 o_acc[4] = {};                         // O^T tile dt: row d=quad*4+r, col q=l15
    float lsum = 0.f;
    const int qg = qt*64 + wv*16 + l15;

    for (int c = 0; c < nc; c++) {
        const int buf = c & 1;
        __syncthreads();                         // Ks[buf] drained (vmcnt) + visible
        if (c + 1 < nc)                          // prefetch in flight across whole chunk
            stage_k(k_ws + kvbase + (size_t)(c+1)*4096, Ks[buf^1], wv, lane);

        // V^T A-frags from global: d = dt*16+l15, keys = c*64 + nt*16 + quad*4 + [0..3]
        bf16x4 vf[4][4];
        const short* vp = vt_ws + kvbase + (size_t)l15*1024 + c*64 + quad*4;
        #pragma unroll
        for (int dt = 0; dt < 4; dt++)
            #pragma unroll
            for (int nt = 0; nt < 4; nt++)
                vf[dt][nt] = *(const bf16x4*)(vp + dt*16384 + nt*16);

        // S^T = K Q^T  (log2 domain, Q pre-scaled)
        f32x4 s_acc[4];
        #pragma unroll
        for (int nt = 0; nt < 4; nt++) {
            bf16x8 kf0 = *(const bf16x8*)&Ks[buf][(nt*16 + l15)*32 + quad*8];
            bf16x8 kf1 = *(const bf16x8*)&Ks[buf][2048 + (nt*16 + l15)*32 + quad*8];
            f32x4 z = {};
            z = MFMA(kf0, aq0, z);
            s_acc[nt] = MFMA(kf1, aq1, z);
        }

        // shift-free softmax numerators; in-register C->B transform
        bf16x4 pb[4];
        #pragma unroll
        for (int nt = 0; nt < 4; nt++) {
            int key0 = c*64 + nt*16 + quad*4;
            #pragma unroll
            for (int r = 0; r < 4; r++) {
                float p = (key0 + r > qg) ? 0.f : exp2f(s_acc[nt][r]);
                lsum += p;
                pb[nt][r] = f2bf(p);
            }
        }

        // O^T += V^T P^T
        #pragma unroll
        for (int dt = 0; dt < 4; dt++)
            #pragma unroll
            for (int nt = 0; nt < 4; nt++)
                o_acc[dt] = MFMA16(vf[dt][nt], pb[nt], o_acc[dt]);
    }

    lsum += __shfl_xor(lsum, 16);                // combine the 4 quads of this q
    lsum += __shfl_xor(lsum, 32);
    float inv = 1.f / lsum;
    short* orow = o_ws + ((size_t)(b*1024 + qg))*2048 + h*64;
    #pragma unroll
    for (int dt = 0; dt < 4; dt++) {
        short4 s4 = make_short4(f2bf(o_acc[dt][0]*inv), f2bf(o_acc[dt][1]*inv),
                                f2bf(o_acc[dt][2]*inv), f2bf(o_acc[dt][3]*inv));
        *(short4*)&orow[dt*16 + quad*4] = s4;
    }
}

extern "C" void kernel_launch(void* const* d_in, const int* in_sizes, int n_in,
                              void* d_out, int out_size, void* d_ws, size_t ws_size,
                              hipStream_t stream) {
    const float* x    = (const float*)d_in[0];
    const float* cosb = (const float*)d_in[1];
    const float* sinb = (const float*)d_in[2];
    const float* Wq   = (const float*)d_in[3];
    const float* Wk   = (const float*)d_in[4];
    const float* Wv   = (const float*)d_in[5];
    const float* Wo   = (const float*)d_in[6];
    float* out = (float*)d_out;

    short* xb   = (short*)d_ws;          // 8,388,608
    short* wqkv = xb   + 8388608;        // 6,291,456  [Wq;Wk;Wv] (3072,2048)
    short* wob  = wqkv + 6291456;        // 4,194,304
    short* q_ws = wob  + 4194304;        // 8,388,608  (B,32,T,64)  pre-scaled
    short* k_ws = q_ws + 8388608;        // 2,097,152  (B,8,T,64)
    short* v_ws = k_ws + 2097152;        // 2,097,152  (B,8,64,T)  TRANSPOSED
    short* o_ws = v_ws + 2097152;        // 8,388,608  (B,T,2048)

    cast_all<<<2048, 256, 0, stream>>>(x, Wq, Wk, Wv, Wo, xb, wqkv, wob);
    gemm_mfma<1><<<dim3(24, 32), 256, 0, stream>>>(xb, wqkv, 4096, 3072, 2048,
                                                   nullptr, q_ws, k_ws, v_ws, cosb, sinb);
    attn_mfma<<<dim3(16, 32, 4), 256, 0, stream>>>(q_ws, k_ws, v_ws, o_ws);
    gemm_mfma<0><<<dim3(16, 32), 256, 0, stream>>>(o_ws, wob, 4096, 2048, 2048,
                                                   out, nullptr, nullptr, nullptr, nullptr, nullptr);
}

// Round 6
// 295.190 us; speedup vs baseline: 1.6034x; 1.6034x over previous
//
#include <hip/hip_runtime.h>
#include <math.h>

#define GAS __attribute__((address_space(1)))
#define LAS __attribute__((address_space(3)))

typedef __attribute__((ext_vector_type(4))) float f32x4;
typedef __attribute__((ext_vector_type(8))) short bf16x8;
typedef __attribute__((ext_vector_type(4))) short bf16x4;

#define MFMA(a,b,c)   __builtin_amdgcn_mfma_f32_16x16x32_bf16((a),(b),(c),0,0,0)
#define MFMA16(a,b,c) __builtin_amdgcn_mfma_f32_16x16x16bf16_1k((a),(b),(c),0,0,0)

#if __has_builtin(__builtin_amdgcn_exp2f)
#define EXP2(x) __builtin_amdgcn_exp2f(x)
#else
#define EXP2(x) exp2f(x)
#endif

__device__ __forceinline__ void gl_lds16(const void* g, void* l) {
    __builtin_amdgcn_global_load_lds((const GAS unsigned*)g, (LAS unsigned*)l, 16, 0, 0);
}

__device__ __forceinline__ short f2bf(float f) {
    union { float f; unsigned u; } v; v.f = f;
    unsigned r = (v.u + 0x7fff + ((v.u >> 16) & 1)) >> 16;   // RNE
    return (short)r;
}

__device__ __forceinline__ void castN(const float* __restrict__ s, short* __restrict__ d,
                                      int n4, int gid, int gsz) {
    for (int i = gid; i < n4; i += gsz) {
        float4 v = ((const float4*)s)[i];
        short4 o = make_short4(f2bf(v.x), f2bf(v.y), f2bf(v.z), f2bf(v.w));
        ((short4*)d)[i] = o;
    }
}

__global__ __launch_bounds__(256)
void cast_all(const float* __restrict__ x,  const float* __restrict__ wq,
              const float* __restrict__ wk, const float* __restrict__ wv,
              const float* __restrict__ wo,
              short* __restrict__ xb, short* __restrict__ wqkv, short* __restrict__ wob) {
    int gid = blockIdx.x*256 + threadIdx.x;
    int gsz = gridDim.x*256;
    castN(x,  xb,               (4096*2048)/4, gid, gsz);
    castN(wq, wqkv,             (2048*2048)/4, gid, gsz);
    castN(wk, wqkv + 2048*2048, (512*2048)/4,  gid, gsz);
    castN(wv, wqkv + 2560*2048, (512*2048)/4,  gid, gsz);
    castN(wo, wob,              (2048*2048)/4, gid, gsz);
}

// m97-style bf16 MFMA GEMM: C(M,N) = A(M,K) @ Bw(N,K)^T, 128x128 tile, BK=32.
// MODE 0: fp32 row-major to Cf (Wo path).
// MODE 1: fused QKV epilogue: RoPE via shfl_xor(1) + bf16 stores.
//         Q pre-scaled by 0.125*log2e (attn softmax runs in exp2 domain, shift=0).
//         V stored TRANSPOSED (B,8,64d,1024t).
template<int MODE>
__global__ __launch_bounds__(256)
void gemm_mfma(const short* __restrict__ A, const short* __restrict__ Bw,
               int M, int N, int K, float* __restrict__ Cf,
               short* __restrict__ qo, short* __restrict__ ko, short* __restrict__ vo,
               const float* __restrict__ cosb, const float* __restrict__ sinb)
{
    __shared__ short As[128*32];
    __shared__ short Bs[128*32];
    const int tid = threadIdx.x;
    const int lane = tid & 63, wv = tid >> 6;
    const int wm = wv >> 1, wn = wv & 1;
    const int m0 = blockIdx.y*128, n0 = blockIdx.x*128;
    const int l15 = lane & 15, quad = lane >> 4;

    f32x4 acc[4][4] = {};

    const int srow = lane >> 2, skc = (lane & 3)*8;
    const short* gA0 = A  + (size_t)(m0 + wv*32 + srow)*K + skc;
    const short* gB0 = Bw + (size_t)(n0 + wv*32 + srow)*K + skc;
    short* lA = As + wv*1024;
    short* lB = Bs + wv*1024;

    for (int k0 = 0; k0 < K; k0 += 32) {
        __syncthreads();
        gl_lds16(gA0 + k0,        lA);
        gl_lds16(gA0 + 16*K + k0, lA + 512);
        gl_lds16(gB0 + k0,        lB);
        gl_lds16(gB0 + 16*K + k0, lB + 512);
        __syncthreads();
        bf16x8 af[4], bfr[4];
        #pragma unroll
        for (int t = 0; t < 4; t++) {
            af[t]  = *(const bf16x8*)&As[(wm*64 + t*16 + l15)*32 + quad*8];
            bfr[t] = *(const bf16x8*)&Bs[(wn*64 + t*16 + l15)*32 + quad*8];
        }
        #pragma unroll
        for (int i = 0; i < 4; i++)
            #pragma unroll
            for (int j = 0; j < 4; j++)
                acc[i][j] = MFMA(af[i], bfr[j], acc[i][j]);
    }

    if (MODE == 0) {
        #pragma unroll
        for (int i = 0; i < 4; i++)
            #pragma unroll
            for (int j = 0; j < 4; j++) {
                int n  = n0 + wn*64 + j*16 + l15;
                int mb = m0 + wm*64 + i*16 + quad*4;
                #pragma unroll
                for (int r = 0; r < 4; r++)
                    Cf[(size_t)(mb + r)*N + n] = acc[i][j][r];
            }
    } else {
        #pragma unroll
        for (int i = 0; i < 4; i++)
            #pragma unroll
            for (int j = 0; j < 4; j++) {
                int n  = n0 + wn*64 + j*16 + l15;   // 16-range never crosses a 64-boundary
                int mb = m0 + wm*64 + i*16 + quad*4;
                if (n >= 2560) {                     // V: transposed store, 4 consecutive t
                    int bq = mb >> 10, t0 = mb & 1023;
                    int hv = (n - 2560) >> 6, d = (n - 2560) & 63;
                    short4 s4 = make_short4(f2bf(acc[i][j][0]), f2bf(acc[i][j][1]),
                                            f2bf(acc[i][j][2]), f2bf(acc[i][j][3]));
                    *(short4*)&vo[(((size_t)(bq*8 + hv)*64 + d) << 10) + t0] = s4;
                } else {
                    #pragma unroll
                    for (int r = 0; r < 4; r++) {
                        int m = mb + r;
                        int b = m >> 10, t = m & 1023;
                        float val = acc[i][j][r];
                        float part = __shfl_xor(val, 1);
                        int d2 = (n & 63) >> 1;
                        float c = cosb[t*32 + d2], s = sinb[t*32 + d2];
                        val = (n & 1) ? (part*s + val*c) : (val*c - part*s);
                        if (n < 2048) {
                            val *= 0.18033688f;      // 64^-0.5 * log2(e)
                            qo[(((size_t)(b*32 + (n>>6))*1024 + t) << 6) + (n & 63)] = f2bf(val);
                        } else {
                            ko[(((size_t)(b*8 + ((n-2048)>>6))*1024 + t) << 6) + ((n-2048) & 63)] = f2bf(val);
                        }
                    }
                }
            }
    }
}

// GQA-fused MFMA flash attention. Block = (b, kvh, qt) = 1024 thr = 16 waves =
// 4 q-heads x 4 row-groups; K/V staged ONCE per block (4-head reuse), both
// double-buffered in LDS -> ONE barrier per 64-key chunk. Transposed-S:
// S^T = K Q^T (C-layout col=q=l15, row=key=quad*4+r) is already the 16x16x16
// B-operand layout, so P feeds O^T = V^T P^T fully in-register (no Ps buffer).
// Staging: waves 0-7 V (b128 global->reg->LDS stride 72, conflict-free),
// waves 8-15 K (1 global_load_lds dwordx4 each, m97 layout). Q from global once.
// Shift-free exp2 softmax (Q pre-scaled); mask peeled to diagonal chunk.
__global__ __launch_bounds__(1024, 8)
void attn_mfma(const short* __restrict__ q_ws, const short* __restrict__ k_ws,
               const short* __restrict__ vt_ws, short* __restrict__ o_ws)
{
    __shared__ short Ks[2][4096];     // [kc2][64k][32d]
    __shared__ short Vs[2][4608];     // [64d][64key] stride 72

    const int tid = threadIdx.x, lane = tid & 63, wv = tid >> 6;
    const int qt = 15 - blockIdx.x;              // big tiles dispatch first
    const int kvh = blockIdx.y, b = blockIdx.z;
    const int hq = wv & 3, rgrp = wv >> 2;
    const int head = kvh*4 + hq;
    const size_t qbase  = ((size_t)(b*32 + head)) << 16;
    const size_t kvbase = ((size_t)(b*8  + kvh )) << 16;
    const short* kt = k_ws  + kvbase;
    const short* vt = vt_ws + kvbase;
    const int l15 = lane & 15, quad = lane >> 4;

    // staging roles
    const bool vstager = (tid < 512);
    const int vrow = tid >> 3, vcol = (tid & 7)*8;           // tid<512: V row d, key chunk
    const int g = tid & 511;                                  // tid>=512: K linear slot
    const int kc = g >> 8, kr = (g >> 2) & 63, dq = (g & 3)*8;

    // chunk 0
    if (vstager) {
        bf16x8 v0 = *(const bf16x8*)(vt + (size_t)vrow*1024 + vcol);
        *(bf16x8*)&Vs[0][vrow*72 + vcol] = v0;
    } else {
        gl_lds16(kt + (size_t)kr*64 + kc*32 + dq, &Ks[0][(wv - 8)*512]);
    }

    // Q B-fragments direct from global (once)
    const short* qp = q_ws + qbase + (size_t)(qt*64 + rgrp*16 + l15)*64 + quad*8;
    bf16x8 aq0 = *(const bf16x8*)qp;
    bf16x8 aq1 = *(const bf16x8*)(qp + 32);

    f32x4 o_acc[4] = {};                          // O^T: row d=quad*4+r (+16dt), col q=l15
    float lsum = 0.f;
    const int qrel = rgrp*16 + l15;

    for (int c = 0; c <= qt; c++) {
        const int cb = c & 1, nb = cb ^ 1;
        __syncthreads();                          // K[c]/V[c] visible; prev reads done
        bf16x8 vreg;
        const bool pre = (c < qt);
        if (pre) {                                // prefetch chunk c+1
            if (vstager)
                vreg = *(const bf16x8*)(vt + (size_t)vrow*1024 + (c+1)*64 + vcol);
            else
                gl_lds16(kt + (size_t)((c+1)*64 + kr)*64 + kc*32 + dq,
                         &Ks[nb][(wv - 8)*512]);
        }

        // S^T = K Q^T  (log2 domain, Q pre-scaled)
        f32x4 s_acc[4];
        #pragma unroll
        for (int nt = 0; nt < 4; nt++) {
            bf16x8 kf0 = *(const bf16x8*)&Ks[cb][(nt*16 + l15)*32 + quad*8];
            bf16x8 kf1 = *(const bf16x8*)&Ks[cb][2048 + (nt*16 + l15)*32 + quad*8];
            f32x4 z = {};
            z = MFMA(kf0, aq0, z);
            s_acc[nt] = MFMA(kf1, aq1, z);
        }

        // shift-free softmax numerators; in-register C->B transform
        bf16x4 pb[4];
        if (c == qt) {                            // diagonal chunk only: causal mask
            #pragma unroll
            for (int nt = 0; nt < 4; nt++)
                #pragma unroll
                for (int r = 0; r < 4; r++) {
                    float p = (nt*16 + quad*4 + r > qrel) ? 0.f : EXP2(s_acc[nt][r]);
                    lsum += p;
                    pb[nt][r] = f2bf(p);
                }
        } else {
            #pragma unroll
            for (int nt = 0; nt < 4; nt++)
                #pragma unroll
                for (int r = 0; r < 4; r++) {
                    float p = EXP2(s_acc[nt][r]);
                    lsum += p;
                    pb[nt][r] = f2bf(p);
                }
        }

        if (pre && vstager)                       // V regs -> LDS (latency now hidden)
            *(bf16x8*)&Vs[nb][vrow*72 + vcol] = vreg;

        // O^T += V^T P^T
        #pragma unroll
        for (int dt = 0; dt < 4; dt++)
            #pragma unroll
            for (int nt = 0; nt < 4; nt++) {
                bf16x4 vf = *(const bf16x4*)&Vs[cb][(dt*16 + l15)*72 + nt*16 + quad*4];
                o_acc[dt] = MFMA16(vf, pb[nt], o_acc[dt]);
            }
    }

    lsum += __shfl_xor(lsum, 16);                 // combine the 4 quads of this q
    lsum += __shfl_xor(lsum, 32);
    float inv = 1.f / lsum;
    short* orow = o_ws + ((size_t)(b*1024 + qt*64 + qrel))*2048 + head*64;
    #pragma unroll
    for (int dt = 0; dt < 4; dt++) {
        short4 s4 = make_short4(f2bf(o_acc[dt][0]*inv), f2bf(o_acc[dt][1]*inv),
                                f2bf(o_acc[dt][2]*inv), f2bf(o_acc[dt][3]*inv));
        *(short4*)&orow[dt*16 + quad*4] = s4;
    }
}

extern "C" void kernel_launch(void* const* d_in, const int* in_sizes, int n_in,
                              void* d_out, int out_size, void* d_ws, size_t ws_size,
                              hipStream_t stream) {
    const float* x    = (const float*)d_in[0];
    const float* cosb = (const float*)d_in[1];
    const float* sinb = (const float*)d_in[2];
    const float* Wq   = (const float*)d_in[3];
    const float* Wk   = (const float*)d_in[4];
    const float* Wv   = (const float*)d_in[5];
    const float* Wo   = (const float*)d_in[6];
    float* out = (float*)d_out;

    short* xb   = (short*)d_ws;          // 8,388,608
    short* wqkv = xb   + 8388608;        // 6,291,456  [Wq;Wk;Wv] (3072,2048)
    short* wob  = wqkv + 6291456;        // 4,194,304
    short* q_ws = wob  + 4194304;        // 8,388,608  (B,32,T,64)  pre-scaled
    short* k_ws = q_ws + 8388608;        // 2,097,152  (B,8,T,64)
    short* v_ws = k_ws + 2097152;        // 2,097,152  (B,8,64,T)  TRANSPOSED
    short* o_ws = v_ws + 2097152;        // 8,388,608  (B,T,2048)

    cast_all<<<2048, 256, 0, stream>>>(x, Wq, Wk, Wv, Wo, xb, wqkv, wob);
    gemm_mfma<1><<<dim3(24, 32), 256, 0, stream>>>(xb, wqkv, 4096, 3072, 2048,
                                                   nullptr, q_ws, k_ws, v_ws, cosb, sinb);
    attn_mfma<<<dim3(16, 8, 4), 1024, 0, stream>>>(q_ws, k_ws, v_ws, o_ws);
    gemm_mfma<0><<<dim3(16, 32), 256, 0, stream>>>(o_ws, wob, 4096, 2048, 2048,
                                                   out, nullptr, nullptr, nullptr, nullptr, nullptr);
}